// Round 14
// baseline (114.939 us; speedup 1.0000x reference)
//
#include <hip/hip_runtime.h>
#include <hip/hip_bf16.h>

typedef __attribute__((ext_vector_type(8))) short short8;
typedef __attribute__((ext_vector_type(4))) float f32x4;
typedef __attribute__((ext_vector_type(2))) unsigned int uint2v;
typedef __attribute__((ext_vector_type(4))) unsigned int uint4v;

#define DK 256   // K dim (D), fixed
#define BM 128
#define BN 128
#define BK 64
#define NKT 4    // DK/BK

// pack two fp32 into one dword of 2x bf16 (truncation; error budget ~2% of |out|)
__device__ __forceinline__ unsigned int pack2bf(float lo, float hi) {
  return __builtin_amdgcn_perm(__builtin_bit_cast(unsigned int, hi),
                               __builtin_bit_cast(unsigned int, lo), 0x07060302);
}

// w (fp32) -> wbf: 16 pre-swizzled 16KB LDS images [ct*4+kt]; csq via atomics.
__global__ void __launch_bounds__(256)
prep_w(const float* __restrict__ w, unsigned short* __restrict__ wbf,
       float* __restrict__ csq) {
  const int b = blockIdx.x;          // b = ct*4 + kt
  const int ct = b >> 2, kt = b & 3;
  const int t = threadIdx.x;
  const int col = t >> 1, khalf = t & 1;
  const float* src = w + (size_t)(ct * BN + col) * DK + kt * BK + khalf * 32;
  unsigned char* dst = (unsigned char*)wbf + (size_t)b * 16384;
  const int sw = (col & 7) << 4;
  float s = 0.f;
  #pragma unroll
  for (int jc = 0; jc < 4; ++jc) {
    f32x4 v0 = *reinterpret_cast<const f32x4*>(src + jc * 8);
    f32x4 v1 = *reinterpret_cast<const f32x4*>(src + jc * 8 + 4);
    s += v0.x*v0.x + v0.y*v0.y + v0.z*v0.z + v0.w*v0.w
       + v1.x*v1.x + v1.y*v1.y + v1.z*v1.z + v1.w*v1.w;
    uint4v pk = { pack2bf(v0.x,v0.y), pack2bf(v0.z,v0.w),
                  pack2bf(v1.x,v1.y), pack2bf(v1.z,v1.w) };
    const int cidx = khalf * 4 + jc;
    *reinterpret_cast<uint4v*>(dst + ((col * 128 + cidx * 16) ^ sw)) = pk;
  }
  s += __shfl_xor(s, 1);
  if (khalf == 0) atomicAdd(&csq[ct * BN + col], s);
}

template<bool PREW>
__global__ void __launch_bounds__(256, 2)
centroid_gemm_pool(const float* __restrict__ x, const float* __restrict__ w,
                   const unsigned short* __restrict__ wbf,
                   const float* __restrict__ csqg, const int* __restrict__ graph,
                   float* __restrict__ outsum, int* __restrict__ cnt,
                   int N, int C, int row_tiles)
{
  __shared__ __align__(16) unsigned char lds_a[2][16384];   // double-buffered (reg-staged)
  __shared__ __align__(16) unsigned char lds_b[2][16384];   // double-buffered (glds)
  __shared__ float xsq_lds[BM];
  __shared__ float csq_lds[BN];

  // XCD grouping: 4 col-tiles of one row-tile on the SAME XCD (L2 reuse of x).
  const int bid = blockIdx.x;
  const int xcd = bid & 7;
  const int j   = bid >> 3;
  const int ct  = j & 3;
  const int rt  = (j >> 2) * 8 + xcd;
  if (rt >= row_tiles) return;

  const int t    = threadIdx.x;
  const int lane = t & 63;
  const int wid  = t >> 6;
  const int wr   = wid >> 1, wc = wid & 1;
  const int h    = lane >> 4, l15 = lane & 15;

  // ---- stage map: thread t covers rows q*16+(t>>4), 4 floats at kloc (t&15)*4 ----
  const int g16 = t >> 4;
  const int sc4 = t & 15;
  const float* aptr[8];
  #pragma unroll
  for (int q = 0; q < 8; ++q) {
    int gr = rt * BM + q * 16 + g16;
    if (gr > N - 1) gr = N - 1;              // clamp; masked via g=-1 later
    aptr[q] = x + (size_t)gr * DK + sc4 * 4;
  }
  const int awbase = (g16 * 128 + sc4 * 8) ^ ((g16 & 7) << 4);

  const int base_a = (wr * 8192 + l15 * 128 + h * 16) ^ ((l15 & 7) << 4);
  const int base_b = (wc * 8192 + l15 * 128 + h * 16) ^ ((l15 & 7) << 4);

  // epilogue graph value: prefetch NOW so the load flies under the whole K-loop
  const int rowg = rt * BM + wr * 64 + lane;
  const int gl   = (rowg < N) ? graph[rowg] : -1;

  f32x4 acc[4][4];
  #pragma unroll
  for (int mt = 0; mt < 4; ++mt)
    #pragma unroll
    for (int nt = 0; nt < 4; ++nt)
      acc[mt][nt] = (f32x4){0.f, 0.f, 0.f, 0.f};
  f32x4 accx[4];                             // X·X^T diag blocks (wc==0; R6/R10-verified)
  #pragma unroll
  for (int mt = 0; mt < 4; ++mt) accx[mt] = (f32x4){0.f, 0.f, 0.f, 0.f};
  float cq[8] = {0.f,0.f,0.f,0.f,0.f,0.f,0.f,0.f};

  f32x4 ra[2][8];                            // 2-deep A prefetch banks (bank = kt&1)
  auto loadA = [&](int bank, int kt) {
    #pragma unroll
    for (int q = 0; q < 8; ++q)
      ra[bank][q] = *reinterpret_cast<const f32x4*>(aptr[q] + kt * BK);
  };
  auto cvtA = [&](int b) {                   // ra[b] -> lds_a[b]
    #pragma unroll
    for (int q = 0; q < 8; ++q) {
      f32x4 v = ra[b][q];
      uint2v pk = { pack2bf(v.x, v.y), pack2bf(v.z, v.w) };
      *reinterpret_cast<uint2v*>(lds_a[b] + awbase + q * 2048) = pk;
    }
  };
  auto stageB = [&](int buf, int kt) {
    const unsigned short* src = wbf + (((size_t)ct * 4 + kt) << 13) + t * 8;
    unsigned char* dst = lds_b[buf] + t * 16;
    #pragma unroll
    for (int p = 0; p < 4; ++p)
      __builtin_amdgcn_global_load_lds(src + p * 2048, dst + p * 4096, 16, 0, 0);
  };
  auto stageBsync = [&](int buf, int kt, bool accum) {  // fallback: convert fp32 w inline
    #pragma unroll
    for (int q = 0; q < 8; ++q) {
      const int colq = q * 16 + g16;
      f32x4 v = *reinterpret_cast<const f32x4*>(
          w + (size_t)(ct * BN + colq) * DK + kt * BK + sc4 * 4);
      if (accum) cq[q] += v.x*v.x + v.y*v.y + v.z*v.z + v.w*v.w;
      uint2v pk = { pack2bf(v.x, v.y), pack2bf(v.z, v.w) };
      *reinterpret_cast<uint2v*>(lds_b[buf] + awbase + q * 2048) = pk;
    }
  };
  auto compute = [&](int buf) {
    __builtin_amdgcn_s_setprio(1);           // T5 (null in R13 but free; keep)
    #pragma unroll
    for (int kk = 0; kk < 2; ++kk) {
      short8 af[4], bfr[4];
      const int ka = base_a ^ (kk << 6);
      const int kb = base_b ^ (kk << 6);
      #pragma unroll
      for (int mt = 0; mt < 4; ++mt)
        af[mt] = *reinterpret_cast<const short8*>(lds_a[buf] + ka + mt * 2048);
      #pragma unroll
      for (int nt = 0; nt < 4; ++nt)
        bfr[nt] = *reinterpret_cast<const short8*>(lds_b[buf] + kb + nt * 2048);
      #pragma unroll
      for (int mt = 0; mt < 4; ++mt)
        #pragma unroll
        for (int nt = 0; nt < 4; ++nt)
          acc[mt][nt] = __builtin_amdgcn_mfma_f32_16x16x32_bf16(af[mt], bfr[nt], acc[mt][nt], 0, 0, 0);
      if (wc == 0) {                         // xsq on the MFMA pipe (diag of X·X^T)
        #pragma unroll
        for (int mt = 0; mt < 4; ++mt)
          accx[mt] = __builtin_amdgcn_mfma_f32_16x16x32_bf16(af[mt], af[mt], accx[mt], 0, 0, 0);
      }
    }
    __builtin_amdgcn_s_setprio(0);
  };

  // ---- prologue: B(0) glds, A(0)->bank0, A(1)->bank1, cvt bank0 ----
  if (PREW) stageB(0, 0); else stageBsync(0, 0, true);
  loadA(0, 0);
  loadA(1, 1);
  cvtA(0);                                   // compiler waits A(0); retires B(0) too

  // ---- single-barrier, 2-deep pipeline ----
  // issue order per iter kt: B(kt+1), A(kt+2) right after the barrier; so
  // top-of-iter vmcnt(8) retires exactly B(kt) while A(kt+2)=8 stays in flight.
  #pragma unroll
  for (int kt = 0; kt < NKT; ++kt) {
    const int cur = kt & 1;
    const int nxt = cur ^ 1;
    if (kt > 0) {
      if (kt < NKT - 1) {
        asm volatile("s_waitcnt vmcnt(8)" ::: "memory");
      } else {
        asm volatile("s_waitcnt vmcnt(0)" ::: "memory");   // only B(3) left
      }
    }
    asm volatile("s_waitcnt lgkmcnt(0)" ::: "memory");
    __builtin_amdgcn_sched_barrier(0);
    __builtin_amdgcn_s_barrier();
    __builtin_amdgcn_sched_barrier(0);
    if (kt < NKT - 1) {
      if (PREW) stageB(nxt, kt + 1);         // +4 vmem, hides under compute
      else      stageBsync(nxt, kt + 1, kt == 0);
      if (kt < NKT - 2) loadA(cur, kt + 2);  // +8 vmem into freed bank cur
    }
    compute(cur);
    if (kt < NKT - 1) cvtA(nxt);             // waits A(kt+1) [vmcnt(12)], leaves rest in flight
  }

  // ---- xsq from X·X^T diagonal: elem (d,d) at lane (d>>2)*16+(d&15), comp d&3 ----
  if (wc == 0 && h == (l15 >> 2)) {
    #pragma unroll
    for (int mt = 0; mt < 4; ++mt)
      xsq_lds[wr * 64 + mt * 16 + l15] = accx[mt][l15 & 3];
  }
  if (!PREW) {
    #pragma unroll
    for (int q = 0; q < 8; ++q) {
      float sb = cq[q];
      sb += __shfl_xor(sb, 1); sb += __shfl_xor(sb, 2);
      sb += __shfl_xor(sb, 4); sb += __shfl_xor(sb, 8);
      if (l15 == 0) csq_lds[q * 16 + g16] = sb;
    }
  }
  __syncthreads();

  // ---- dist = sqrt(max(xsq + csq - 2*dot, 0)) ----
  float xs[4][4], cs[4];
  #pragma unroll
  for (int mt = 0; mt < 4; ++mt)
    #pragma unroll
    for (int i = 0; i < 4; ++i)
      xs[mt][i] = xsq_lds[wr * 64 + mt * 16 + h * 4 + i];
  #pragma unroll
  for (int nt = 0; nt < 4; ++nt)
    cs[nt] = PREW ? csqg[ct * BN + wc * 64 + nt * 16 + l15]
                  : csq_lds[wc * 64 + nt * 16 + l15];
  #pragma unroll
  for (int mt = 0; mt < 4; ++mt)
    #pragma unroll
    for (int nt = 0; nt < 4; ++nt)
      #pragma unroll
      for (int i = 0; i < 4; ++i) {
        float dd = fmaf(-2.0f, acc[mt][nt][i], xs[mt][i] + cs[nt]);
        acc[mt][nt][i] = __builtin_amdgcn_sqrtf(fmaxf(dd, 0.f));
      }

  // ---- wave-local segment reduction over sorted runs (rows wr*64..+64) ----
  const int col0 = ct * BN + wc * 64;
  const int glp  = __shfl_up(gl, 1);
  const unsigned long long bmw = __ballot(lane == 0 || gl != glp);

  int s0 = 0;
  while (s0 < 64) {
    unsigned long long rest = (s0 < 63) ? (bmw >> (s0 + 1)) : 0ULL;
    const int e = rest ? s0 + 1 + __builtin_ctzll(rest) : 64;
    const int g = __shfl(gl, s0);
    if (g >= 0) {
      float p[4] = {0.f, 0.f, 0.f, 0.f};
      #pragma unroll
      for (int mt = 0; mt < 4; ++mt)
        #pragma unroll
        for (int i = 0; i < 4; ++i) {
          const int row = mt * 16 + h * 4 + i;
          const bool in = (row >= s0) && (row < e);
          #pragma unroll
          for (int nt = 0; nt < 4; ++nt)
            p[nt] += in ? acc[mt][nt][i] : 0.f;
        }
      #pragma unroll
      for (int nt = 0; nt < 4; ++nt) {
        p[nt] += __shfl_xor(p[nt], 16);
        p[nt] += __shfl_xor(p[nt], 32);
      }
      if (lane < 16) {
        #pragma unroll
        for (int nt = 0; nt < 4; ++nt)
          atomicAdd(&outsum[(size_t)g * C + col0 + nt * 16 + lane], p[nt]);
      }
      if (cnt && ct == 0 && wc == 0 && lane == 0)
        atomicAdd(&cnt[g], e - s0);
    }
    s0 = e;
  }
}

__global__ void __launch_bounds__(256)
divide_counts(float* __restrict__ out, const int* __restrict__ cnt, int C)
{
  const int g = blockIdx.x;
  const int c0 = cnt[g];
  const float inv = 1.0f / (float)(c0 > 1 ? c0 : 1);
  for (int c = threadIdx.x; c < C; c += 256)
    out[(size_t)g * C + c] *= inv;
}

__global__ void __launch_bounds__(128)
divide_by_count(float* __restrict__ out, const int* __restrict__ graph, int N, int C)
{
  const int g = blockIdx.x;
  int lo = 0, hi = N;
  while (lo < hi) { int mid = (lo + hi) >> 1; if (graph[mid] < g) lo = mid + 1; else hi = mid; }
  const int lb = lo;
  hi = N;
  while (lo < hi) { int mid = (lo + hi) >> 1; if (graph[mid] <= g) lo = mid + 1; else hi = mid; }
  const int cntg = lo - lb;
  const float inv = 1.0f / (float)(cntg > 1 ? cntg : 1);
  for (int c = threadIdx.x; c < C; c += blockDim.x)
    out[(size_t)g * C + c] *= inv;
}

extern "C" void kernel_launch(void* const* d_in, const int* in_sizes, int n_in,
                              void* d_out, int out_size, void* d_ws, size_t ws_size,
                              hipStream_t stream) {
  const float* x     = (const float*)d_in[0];
  const float* w     = (const float*)d_in[1];
  const int*   graph = (const int*)d_in[2];
  const int N = in_sizes[2];                 // 200000
  const int D = in_sizes[0] / N;             // 256
  const int C = in_sizes[1] / D;             // 512
  const int G = out_size / C;                // 512

  const int row_tiles = (N + BM - 1) / BM;   // 1563
  const int rgroups   = (row_tiles + 7) / 8; // 196
  const int grid      = rgroups * 8 * (C / BN);

  const size_t wbf_bytes = (size_t)16 * 16384;          // 256 KB
  const size_t csq_off   = wbf_bytes;
  const size_t cnt_off   = wbf_bytes + (size_t)C * 4;
  const bool prew     = ws_size >= cnt_off + (size_t)G * 4;
  const bool have_cnt = prew || ws_size >= (size_t)G * 4;

  unsigned short* wbf = (unsigned short*)d_ws;
  float* csq = (float*)((char*)d_ws + csq_off);
  int*   cnt = prew ? (int*)((char*)d_ws + cnt_off)
                    : (have_cnt ? (int*)d_ws : nullptr);

  hipMemsetAsync(d_out, 0, (size_t)out_size * sizeof(float), stream);
  if (cnt) hipMemsetAsync(cnt, 0, (size_t)G * sizeof(int), stream);

  if (prew) {
    hipMemsetAsync(csq, 0, (size_t)C * sizeof(float), stream);
    prep_w<<<dim3(16), dim3(256), 0, stream>>>(w, wbf, csq);
    centroid_gemm_pool<true><<<dim3(grid), dim3(256), 0, stream>>>(
        x, w, wbf, csq, graph, (float*)d_out, cnt, N, C, row_tiles);
  } else {
    centroid_gemm_pool<false><<<dim3(grid), dim3(256), 0, stream>>>(
        x, w, wbf, csq, graph, (float*)d_out, cnt, N, C, row_tiles);
  }

  if (cnt)
    divide_counts<<<dim3(G), dim3(256), 0, stream>>>((float*)d_out, cnt, C);
  else
    divide_by_count<<<dim3(G), dim3(128), 0, stream>>>((float*)d_out, graph, N, C);
}

// Round 15
// 98.483 us; speedup vs baseline: 1.1671x; 1.1671x over previous
//
#include <hip/hip_runtime.h>
#include <hip/hip_bf16.h>

typedef __attribute__((ext_vector_type(8))) short short8;
typedef __attribute__((ext_vector_type(4))) float f32x4;
typedef __attribute__((ext_vector_type(2))) unsigned int uint2v;
typedef __attribute__((ext_vector_type(4))) unsigned int uint4v;

#define DK 256   // K dim (D), fixed
#define BM 128
#define BN 128
#define BK 64
#define NKT 4    // DK/BK

// pack two fp32 into one dword of 2x bf16 (truncation; error budget ~2% of |out|)
__device__ __forceinline__ unsigned int pack2bf(float lo, float hi) {
  return __builtin_amdgcn_perm(__builtin_bit_cast(unsigned int, hi),
                               __builtin_bit_cast(unsigned int, lo), 0x07060302);
}

// raw buffer descriptor: base, stride=0, num_records=bytes, raw-dword word3
__device__ __forceinline__ uint4v make_srsrc(const void* p, unsigned bytes) {
  union { const void* p; unsigned u[2]; } a; a.p = p;
  uint4v r;
  r.x = a.u[0];
  r.y = a.u[1] & 0xFFFFu;    // base[47:32]; stride=0 in [29:16]
  r.z = bytes;               // num_records (bytes when stride==0) -> HW bounds check
  r.w = 0x00020000u;         // raw untyped dword access
  return r;
}

// w (fp32) -> wbf: 16 pre-swizzled 16KB LDS images [ct*4+kt]; csq via atomics.
__global__ void __launch_bounds__(256)
prep_w(const float* __restrict__ w, unsigned short* __restrict__ wbf,
       float* __restrict__ csq) {
  const int b = blockIdx.x;          // b = ct*4 + kt
  const int ct = b >> 2, kt = b & 3;
  const int t = threadIdx.x;
  const int col = t >> 1, khalf = t & 1;
  const float* src = w + (size_t)(ct * BN + col) * DK + kt * BK + khalf * 32;
  unsigned char* dst = (unsigned char*)wbf + (size_t)b * 16384;
  const int sw = (col & 7) << 4;
  float s = 0.f;
  #pragma unroll
  for (int jc = 0; jc < 4; ++jc) {
    f32x4 v0 = *reinterpret_cast<const f32x4*>(src + jc * 8);
    f32x4 v1 = *reinterpret_cast<const f32x4*>(src + jc * 8 + 4);
    s += v0.x*v0.x + v0.y*v0.y + v0.z*v0.z + v0.w*v0.w
       + v1.x*v1.x + v1.y*v1.y + v1.z*v1.z + v1.w*v1.w;
    uint4v pk = { pack2bf(v0.x,v0.y), pack2bf(v0.z,v0.w),
                  pack2bf(v1.x,v1.y), pack2bf(v1.z,v1.w) };
    const int cidx = khalf * 4 + jc;
    *reinterpret_cast<uint4v*>(dst + ((col * 128 + cidx * 16) ^ sw)) = pk;
  }
  s += __shfl_xor(s, 1);
  if (khalf == 0) atomicAdd(&csq[ct * BN + col], s);
}

template<bool PREW>
__global__ void __launch_bounds__(256, 2)
centroid_gemm_pool(const float* __restrict__ x, const float* __restrict__ w,
                   const unsigned short* __restrict__ wbf,
                   const float* __restrict__ csqg, const int* __restrict__ graph,
                   float* __restrict__ outsum, int* __restrict__ cnt,
                   int N, int C, int row_tiles)
{
  __shared__ __align__(16) unsigned char lds_a[16384];      // single-buffered (reg-staged)
  __shared__ __align__(16) unsigned char lds_b[2][16384];   // double-buffered (glds)
  __shared__ float xsq_lds[BM];
  __shared__ float csq_lds[BN];

  // XCD grouping: 4 col-tiles of one row-tile on the SAME XCD (L2 reuse of x).
  const int bid = blockIdx.x;
  const int xcd = bid & 7;
  const int j   = bid >> 3;
  const int ct  = j & 3;
  const int rt  = (j >> 2) * 8 + xcd;
  if (rt >= row_tiles) return;

  const int t    = threadIdx.x;
  const int lane = t & 63;
  const int wid  = t >> 6;
  const int wr   = wid >> 1, wc = wid & 1;
  const int h    = lane >> 4, l15 = lane & 15;

  // ---- stage map: thread t covers rows q*16+(t>>4), 4 floats at kloc (t&15)*4 ----
  const int g16 = t >> 4;
  const int sc4 = t & 15;
  // A addressing: SRSRC (4 SGPRs) + single 32-bit voffset VGPR; per-(q,kt)
  // deltas go in the uniform soffset field. OOB rows -> HW bounds check -> 0.
  const uint4v xrsrc = make_srsrc(x, (unsigned)((size_t)N * DK * 4));
  const unsigned voffA = (unsigned)(rt * BM + g16) * (DK * 4) + sc4 * 16;

  const int awbase = (g16 * 128 + sc4 * 8) ^ ((g16 & 7) << 4);
  const int base_a = (wr * 8192 + l15 * 128 + h * 16) ^ ((l15 & 7) << 4);
  const int base_b = (wc * 8192 + l15 * 128 + h * 16) ^ ((l15 & 7) << 4);

  // epilogue graph value: load it BEFORE the manual vmcnt ledger starts, and
  // force completion here so it cannot perturb the counted waits below.
  const int rowg = rt * BM + wr * 64 + lane;
  int gl = (rowg < N) ? graph[rowg] : -1;
  asm volatile("" : "+v"(gl));

  f32x4 acc[4][4];
  #pragma unroll
  for (int mt = 0; mt < 4; ++mt)
    #pragma unroll
    for (int nt = 0; nt < 4; ++nt)
      acc[mt][nt] = (f32x4){0.f, 0.f, 0.f, 0.f};
  f32x4 accx[4];                             // X·X^T diag blocks (wc==0; R6/R10-verified)
  #pragma unroll
  for (int mt = 0; mt < 4; ++mt) accx[mt] = (f32x4){0.f, 0.f, 0.f, 0.f};
  float cq[8] = {0.f,0.f,0.f,0.f,0.f,0.f,0.f,0.f};

  f32x4 ra[8];                               // single prefetch bank
  auto loadA = [&](int kt) {                 // 8 buffer_loads, manual vmcnt tracking
    #pragma unroll
    for (int q = 0; q < 8; ++q)
      asm volatile("buffer_load_dwordx4 %0, %1, %2, %3 offen"
                   : "=v"(ra[q])
                   : "v"(voffA), "s"(xrsrc), "s"(q * 16 * DK * 4 + kt * BK * 4));
  };
  auto cvtA = [&]() {
    #pragma unroll
    for (int q = 0; q < 8; ++q) {
      f32x4 v = ra[q];
      uint2v pk = { pack2bf(v.x, v.y), pack2bf(v.z, v.w) };
      *reinterpret_cast<uint2v*>(lds_a + awbase + q * 2048) = pk;
    }
  };
  auto stageB = [&](int buf, int kt) {
    const unsigned short* src = wbf + (((size_t)ct * 4 + kt) << 13) + t * 8;
    unsigned char* dst = lds_b[buf] + t * 16;
    #pragma unroll
    for (int p = 0; p < 4; ++p)
      __builtin_amdgcn_global_load_lds(src + p * 2048, dst + p * 4096, 16, 0, 0);
  };
  auto stageBsync = [&](int buf, int kt, bool accum) {  // fallback: convert fp32 w inline
    #pragma unroll
    for (int q = 0; q < 8; ++q) {
      const int colq = q * 16 + g16;
      f32x4 v = *reinterpret_cast<const f32x4*>(
          w + (size_t)(ct * BN + colq) * DK + kt * BK + sc4 * 4);
      if (accum) cq[q] += v.x*v.x + v.y*v.y + v.z*v.z + v.w*v.w;
      uint2v pk = { pack2bf(v.x, v.y), pack2bf(v.z, v.w) };
      *reinterpret_cast<uint2v*>(lds_b[buf] + awbase + q * 2048) = pk;
    }
  };
  auto compute = [&](unsigned char* lb) {
    __builtin_amdgcn_s_setprio(1);
    #pragma unroll
    for (int kk = 0; kk < 2; ++kk) {
      short8 af[4], bfr[4];
      const int ka = base_a ^ (kk << 6);
      const int kb = base_b ^ (kk << 6);
      #pragma unroll
      for (int mt = 0; mt < 4; ++mt)
        af[mt] = *reinterpret_cast<const short8*>(lds_a + ka + mt * 2048);
      #pragma unroll
      for (int nt = 0; nt < 4; ++nt)
        bfr[nt] = *reinterpret_cast<const short8*>(lb + kb + nt * 2048);
      #pragma unroll
      for (int mt = 0; mt < 4; ++mt)
        #pragma unroll
        for (int nt = 0; nt < 4; ++nt)
          acc[mt][nt] = __builtin_amdgcn_mfma_f32_16x16x32_bf16(af[mt], bfr[nt], acc[mt][nt], 0, 0, 0);
      if (wc == 0) {                         // xsq on the MFMA pipe (diag of X·X^T)
        #pragma unroll
        for (int mt = 0; mt < 4; ++mt)
          accx[mt] = __builtin_amdgcn_mfma_f32_16x16x32_bf16(af[mt], af[mt], accx[mt], 0, 0, 0);
      }
    }
    __builtin_amdgcn_s_setprio(0);
  };

  // ---- prologue: A(0) asm loads (+8), then B(0) glds (+4) ----
  loadA(0);
  if (PREW) stageB(0, 0); else stageBsync(0, 0, true);

  // ---- 2-barrier counted pipeline; manual vmcnt ledger (asm loads untracked):
  // iter entry: [A(kt)=8, B(kt)=4] -> vmcnt(4) retires exactly A(kt);
  // after +A(kt+1)+B(kt+1): vmcnt(12) retires exactly B(kt). ----
  #pragma unroll
  for (int kt = 0; kt < NKT; ++kt) {
    const int cur = kt & 1;
    if (PREW) { asm volatile("s_waitcnt vmcnt(4)" ::: "memory"); }
    else      { asm volatile("s_waitcnt vmcnt(0)" ::: "memory"); }
    __builtin_amdgcn_sched_barrier(0);
    cvtA();                                  // ra -> lds_a (safe: barrier2 of kt-1 passed)
    if (kt + 1 < NKT) {
      loadA(kt + 1);                         // +8 vmem
      if (PREW) stageB(cur ^ 1, kt + 1);     // +4 vmem
      else      stageBsync(cur ^ 1, kt + 1, kt == 0);
      if (PREW) { asm volatile("s_waitcnt vmcnt(12)" ::: "memory"); }
      else      { asm volatile("s_waitcnt vmcnt(0)" ::: "memory"); }
    } else {
      asm volatile("s_waitcnt vmcnt(0)" ::: "memory");   // drain last B glds
    }
    asm volatile("s_waitcnt lgkmcnt(0)" ::: "memory");
    __builtin_amdgcn_sched_barrier(0);
    __builtin_amdgcn_s_barrier();
    __builtin_amdgcn_sched_barrier(0);
    compute(lds_b[cur]);
    __builtin_amdgcn_sched_barrier(0);
    __builtin_amdgcn_s_barrier();            // protects lds_a/lds_b rewrite next iter
    __builtin_amdgcn_sched_barrier(0);
  }

  // ---- xsq from X·X^T diagonal: elem (d,d) at lane (d>>2)*16+(d&15), comp d&3 ----
  if (wc == 0 && h == (l15 >> 2)) {
    #pragma unroll
    for (int mt = 0; mt < 4; ++mt)
      xsq_lds[wr * 64 + mt * 16 + l15] = accx[mt][l15 & 3];
  }
  if (!PREW) {
    #pragma unroll
    for (int q = 0; q < 8; ++q) {
      float sb = cq[q];
      sb += __shfl_xor(sb, 1); sb += __shfl_xor(sb, 2);
      sb += __shfl_xor(sb, 4); sb += __shfl_xor(sb, 8);
      if (l15 == 0) csq_lds[q * 16 + g16] = sb;
    }
  }
  __syncthreads();

  // ---- dist = sqrt(max(xsq + csq - 2*dot, 0)) ----
  float xs[4][4], cs[4];
  #pragma unroll
  for (int mt = 0; mt < 4; ++mt)
    #pragma unroll
    for (int i = 0; i < 4; ++i)
      xs[mt][i] = xsq_lds[wr * 64 + mt * 16 + h * 4 + i];
  #pragma unroll
  for (int nt = 0; nt < 4; ++nt)
    cs[nt] = PREW ? csqg[ct * BN + wc * 64 + nt * 16 + l15]
                  : csq_lds[wc * 64 + nt * 16 + l15];
  #pragma unroll
  for (int mt = 0; mt < 4; ++mt)
    #pragma unroll
    for (int nt = 0; nt < 4; ++nt)
      #pragma unroll
      for (int i = 0; i < 4; ++i) {
        float dd = fmaf(-2.0f, acc[mt][nt][i], xs[mt][i] + cs[nt]);
        acc[mt][nt][i] = __builtin_amdgcn_sqrtf(fmaxf(dd, 0.f));
      }

  // ---- wave-local segment reduction over sorted runs (rows wr*64..+64) ----
  const int col0 = ct * BN + wc * 64;
  const int glp  = __shfl_up(gl, 1);
  const unsigned long long bmw = __ballot(lane == 0 || gl != glp);

  int s0 = 0;
  while (s0 < 64) {
    unsigned long long rest = (s0 < 63) ? (bmw >> (s0 + 1)) : 0ULL;
    const int e = rest ? s0 + 1 + __builtin_ctzll(rest) : 64;
    const int g = __shfl(gl, s0);
    if (g >= 0) {
      float p[4] = {0.f, 0.f, 0.f, 0.f};
      #pragma unroll
      for (int mt = 0; mt < 4; ++mt)
        #pragma unroll
        for (int i = 0; i < 4; ++i) {
          const int row = mt * 16 + h * 4 + i;
          const bool in = (row >= s0) && (row < e);
          #pragma unroll
          for (int nt = 0; nt < 4; ++nt)
            p[nt] += in ? acc[mt][nt][i] : 0.f;
        }
      #pragma unroll
      for (int nt = 0; nt < 4; ++nt) {
        p[nt] += __shfl_xor(p[nt], 16);
        p[nt] += __shfl_xor(p[nt], 32);
      }
      if (lane < 16) {
        #pragma unroll
        for (int nt = 0; nt < 4; ++nt)
          atomicAdd(&outsum[(size_t)g * C + col0 + nt * 16 + lane], p[nt]);
      }
      if (cnt && ct == 0 && wc == 0 && lane == 0)
        atomicAdd(&cnt[g], e - s0);
    }
    s0 = e;
  }
}

__global__ void __launch_bounds__(256)
divide_counts(float* __restrict__ out, const int* __restrict__ cnt, int C)
{
  const int g = blockIdx.x;
  const int c0 = cnt[g];
  const float inv = 1.0f / (float)(c0 > 1 ? c0 : 1);
  for (int c = threadIdx.x; c < C; c += 256)
    out[(size_t)g * C + c] *= inv;
}

__global__ void __launch_bounds__(128)
divide_by_count(float* __restrict__ out, const int* __restrict__ graph, int N, int C)
{
  const int g = blockIdx.x;
  int lo = 0, hi = N;
  while (lo < hi) { int mid = (lo + hi) >> 1; if (graph[mid] < g) lo = mid + 1; else hi = mid; }
  const int lb = lo;
  hi = N;
  while (lo < hi) { int mid = (lo + hi) >> 1; if (graph[mid] <= g) lo = mid + 1; else hi = mid; }
  const int cntg = lo - lb;
  const float inv = 1.0f / (float)(cntg > 1 ? cntg : 1);
  for (int c = threadIdx.x; c < C; c += blockDim.x)
    out[(size_t)g * C + c] *= inv;
}

extern "C" void kernel_launch(void* const* d_in, const int* in_sizes, int n_in,
                              void* d_out, int out_size, void* d_ws, size_t ws_size,
                              hipStream_t stream) {
  const float* x     = (const float*)d_in[0];
  const float* w     = (const float*)d_in[1];
  const int*   graph = (const int*)d_in[2];
  const int N = in_sizes[2];                 // 200000
  const int D = in_sizes[0] / N;             // 256
  const int C = in_sizes[1] / D;             // 512
  const int G = out_size / C;                // 512

  const int row_tiles = (N + BM - 1) / BM;   // 1563
  const int rgroups   = (row_tiles + 7) / 8; // 196
  const int grid      = rgroups * 8 * (C / BN);

  const size_t wbf_bytes = (size_t)16 * 16384;          // 256 KB
  const size_t csq_off   = wbf_bytes;
  const size_t cnt_off   = wbf_bytes + (size_t)C * 4;
  const bool prew     = ws_size >= cnt_off + (size_t)G * 4;
  const bool have_cnt = prew || ws_size >= (size_t)G * 4;

  unsigned short* wbf = (unsigned short*)d_ws;
  float* csq = (float*)((char*)d_ws + csq_off);
  int*   cnt = prew ? (int*)((char*)d_ws + cnt_off)
                    : (have_cnt ? (int*)d_ws : nullptr);

  hipMemsetAsync(d_out, 0, (size_t)out_size * sizeof(float), stream);
  if (cnt) hipMemsetAsync(cnt, 0, (size_t)G * sizeof(int), stream);

  if (prew) {
    hipMemsetAsync(csq, 0, (size_t)C * sizeof(float), stream);
    prep_w<<<dim3(16), dim3(256), 0, stream>>>(w, wbf, csq);
    centroid_gemm_pool<true><<<dim3(grid), dim3(256), 0, stream>>>(
        x, w, wbf, csq, graph, (float*)d_out, cnt, N, C, row_tiles);
  } else {
    centroid_gemm_pool<false><<<dim3(grid), dim3(256), 0, stream>>>(
        x, w, wbf, csq, graph, (float*)d_out, cnt, N, C, row_tiles);
  }

  if (cnt)
    divide_counts<<<dim3(G), dim3(256), 0, stream>>>((float*)d_out, cnt, C);
  else
    divide_by_count<<<dim3(G), dim3(128), 0, stream>>>((float*)d_out, graph, N, C);
}